// Round 5
// baseline (348.998 us; speedup 1.0000x reference)
//
#include <hip/hip_runtime.h>

typedef float f32x4 __attribute__((ext_vector_type(4)));
typedef __bf16 bf16x8 __attribute__((ext_vector_type(8)));
typedef unsigned short u16x8 __attribute__((ext_vector_type(8)));
typedef unsigned int u32x4 __attribute__((ext_vector_type(4)));

#define NBH 16
#define NSEQ 4096
#define DH 64

__device__ __forceinline__ unsigned int cvtpk(float lo, float hi) {
  unsigned int r;
  asm("v_cvt_pk_bf16_f32 %0, %1, %2" : "=v"(r) : "v"(lo), "v"(hi));
  return r;
}
__device__ __forceinline__ bf16x8 pk8(const float* f) {
  union { unsigned int u[4]; bf16x8 b; } x;
#pragma unroll
  for (int i = 0; i < 4; ++i) x.u[i] = cvtpk(f[2 * i], f[2 * i + 1]);
  return x.b;
}

// Light barrier: drain LDS ops only; global stores stay in flight.
__device__ __forceinline__ void lbar() {
  __builtin_amdgcn_sched_barrier(0);
  asm volatile("s_waitcnt lgkmcnt(0)" ::: "memory");
  __builtin_amdgcn_s_barrier();
  __builtin_amdgcn_sched_barrier(0);
}

// One 64-row q-tile per 256-thread block; 1024 blocks; ~4 blocks/CU.
// qt mapping balances per-CU total loop iterations under breadth-first
// dispatch: CU gets {t, t, 63-t, 63-t} -> 130 iters constant.
__global__ __launch_bounds__(256, 4) void sdpa_fused(
    const float* __restrict__ qg, const float* __restrict__ kg,
    const float* __restrict__ vg, float* __restrict__ outg) {
  const int bid = blockIdx.x;
  const int xcd = bid & 7;
  const int ii = bid >> 3;       // 0..127 within XCD
  const int hh = ii >> 6;        // head
  const int tt = ii & 63;
  const int qt = (tt < 32) ? tt : 95 - tt;   // bijective, CU-balanced
  const int b = 2 * xcd + hh;
  const int qr0 = qt * 64;
  const int nkt = qt + 1;

  const int tid = threadIdx.x;
  const int w = tid >> 6, lane = tid & 63;
  const int g = lane >> 4, c = lane & 15;
  const int wr0 = 16 * w;

  const float* qbp = qg + (size_t)b * NSEQ * DH;
  const float* kbp = kg + (size_t)b * NSEQ * DH;
  const float* vbp = vg + (size_t)b * NSEQ * DH;
  float* outb = outg + (size_t)b * NSEQ * DH;
  float* attnb = outg + (size_t)NBH * NSEQ * DH + (size_t)b * NSEQ * NSEQ;

  __shared__ unsigned short Kl[2][64][72];  // 18.4 KB (double-buffered)
  __shared__ unsigned int Vt[64][37];       // 9.5 KB  (single buffer)
  __shared__ unsigned short Pl[64][72];     // 9.2 KB  (wave-private slabs)

  // ---- Q fragments: row = qr0+wr0+c, k = 32ks+8g+e ----
  bf16x8 aq[2];
  {
    const float* qrow = qbp + (size_t)(qr0 + wr0 + c) * DH;
#pragma unroll
    for (int ks = 0; ks < 2; ++ks) {
      float f[8];
      *(float4*)f = *(const float4*)(qrow + 32 * ks + 8 * g);
      *(float4*)(f + 4) = *(const float4*)(qrow + 32 * ks + 8 * g + 4);
      aq[ks] = pk8(f);
    }
  }

  // ---- staging maps (256 threads, 64x64 f32 tiles) ----
  const int kj = tid >> 2, kcs = tid & 3;   // K: row kj, 16-float chunk
  const int vp = tid >> 3, vch = tid & 7;   // V: row-pair vp, 8-float chunk
  float kf[16], vf0[8], vf1[8];

  auto loadK = [&](int kt) {
    const float* s = kbp + (size_t)(kt * 64 + kj) * DH + kcs * 16;
#pragma unroll
    for (int i = 0; i < 4; ++i) *(float4*)(kf + 4 * i) = ((const float4*)s)[i];
  };
  auto writeK = [&](int cur) {
    unsigned int* dst = (unsigned int*)&Kl[cur][kj][kcs * 16];
#pragma unroll
    for (int i = 0; i < 8; ++i) dst[i] = cvtpk(kf[2 * i], kf[2 * i + 1]);
  };
  auto loadV = [&](int kt) {
    const float* s0 = vbp + (size_t)(kt * 64 + 2 * vp) * DH + vch * 8;
    *(float4*)vf0 = ((const float4*)s0)[0];
    *(float4*)(vf0 + 4) = ((const float4*)s0)[1];
    *(float4*)vf1 = ((const float4*)(s0 + DH))[0];
    *(float4*)(vf1 + 4) = ((const float4*)(s0 + DH))[1];
  };
  auto writeV = [&]() {
#pragma unroll
    for (int e = 0; e < 8; ++e) Vt[vch * 8 + e][vp] = cvtpk(vf0[e], vf1[e]);
  };

  // ================= pass 1: l = sum(exp(s)) =================
  float part[4] = {0.f, 0.f, 0.f, 0.f};
  loadK(0);
  for (int kt = 0; kt < nkt; ++kt) {
    const int cur = kt & 1;
    writeK(cur);
    lbar();
    if (kt + 1 < nkt) loadK(kt + 1);
    f32x4 acc[4];
#pragma unroll
    for (int ct = 0; ct < 4; ++ct) acc[ct] = (f32x4){0.f, 0.f, 0.f, 0.f};
#pragma unroll
    for (int ks = 0; ks < 2; ++ks)
#pragma unroll
      for (int ct = 0; ct < 4; ++ct) {
        u16x8 u = *(const u16x8*)&Kl[cur][16 * ct + c][32 * ks + 8 * g];
        acc[ct] = __builtin_amdgcn_mfma_f32_16x16x32_bf16(aq[ks], __builtin_bit_cast(bf16x8, u), acc[ct], 0, 0, 0);
      }
#pragma unroll
    for (int ct = 0; ct < 4; ++ct)
#pragma unroll
      for (int r = 0; r < 4; ++r) {
        const int j = kt * 64 + 16 * ct + c;
        const int i = qr0 + wr0 + 4 * g + r;
        part[r] += (j <= i) ? __expf(acc[ct][r] * 0.125f) : 0.f;
      }
  }
  float rinv[4];
#pragma unroll
  for (int r = 0; r < 4; ++r) {
    float s = part[r];
    s += __shfl_xor(s, 1); s += __shfl_xor(s, 2);
    s += __shfl_xor(s, 4); s += __shfl_xor(s, 8);
    rinv[r] = 1.f / s;
  }

  __syncthreads();  // full drain between passes (Kl reuse)

  // ================= pass 2: attn + PV =================
  loadK(0);
  loadV(0);
  f32x4 oacc[4];
#pragma unroll
  for (int ct = 0; ct < 4; ++ct) oacc[ct] = (f32x4){0.f, 0.f, 0.f, 0.f};

  for (int kt = 0; kt < nkt; ++kt) {
    const int cur = kt & 1;
    writeK(cur);
    writeV();      // protected by lbar(B) of previous iteration
    lbar();        // A: staging visible
    if (kt + 1 < nkt) { loadK(kt + 1); loadV(kt + 1); }

    f32x4 acc[4];
#pragma unroll
    for (int ct = 0; ct < 4; ++ct) acc[ct] = (f32x4){0.f, 0.f, 0.f, 0.f};
#pragma unroll
    for (int ks = 0; ks < 2; ++ks)
#pragma unroll
      for (int ct = 0; ct < 4; ++ct) {
        u16x8 u = *(const u16x8*)&Kl[cur][16 * ct + c][32 * ks + 8 * g];
        acc[ct] = __builtin_amdgcn_mfma_f32_16x16x32_bf16(aq[ks], __builtin_bit_cast(bf16x8, u), acc[ct], 0, 0, 0);
      }

#pragma unroll
    for (int ct = 0; ct < 4; ++ct)
#pragma unroll
      for (int r = 0; r < 4; ++r) {
        const int jl = 16 * ct + c;
        const int i = qr0 + wr0 + 4 * g + r;
        const int j = kt * 64 + jl;
        const float p = (j <= i) ? __expf(acc[ct][r] * 0.125f) * rinv[r] : 0.f;
        Pl[wr0 + 4 * g + r][jl] = (unsigned short)cvtpk(p, p);
        attnb[(size_t)i * NSEQ + j] = p;  // stays in flight across lbar
      }

    // wave-synchronous transpose read of own Pl slab
    bf16x8 ap[2];
#pragma unroll
    for (int ks = 0; ks < 2; ++ks)
      ap[ks] = __builtin_bit_cast(bf16x8, *(const u16x8*)&Pl[wr0 + c][32 * ks + 8 * g]);
#pragma unroll
    for (int ks = 0; ks < 2; ++ks)
#pragma unroll
      for (int ct = 0; ct < 4; ++ct) {
        u16x8 bv = *(const u16x8*)&Vt[16 * ct + c][16 * ks + 4 * g];
        oacc[ct] = __builtin_amdgcn_mfma_f32_16x16x32_bf16(ap[ks], __builtin_bit_cast(bf16x8, bv), oacc[ct], 0, 0, 0);
      }
    lbar();        // B: Vt/Kl reads done before next writeV/writeK
  }

  // ---- out write ----
#pragma unroll
  for (int ct = 0; ct < 4; ++ct)
#pragma unroll
    for (int r = 0; r < 4; ++r) {
      const int i = qr0 + wr0 + 4 * g + r;
      outb[(size_t)i * DH + 16 * ct + c] = oacc[ct][r];
    }

  // ---- zero-fill strict upper triangle (small-qt blocks do big fills) ----
  const int zc0 = 64 * (qt + 1);
  if (zc0 < NSEQ) {
    const int zw4 = (NSEQ - zc0) >> 2;
    const float4 z = {0.f, 0.f, 0.f, 0.f};
    for (int r = 0; r < 64; ++r) {
      float4* dst = (float4*)(attnb + (size_t)(qr0 + r) * NSEQ + zc0);
      for (int c4 = tid; c4 < zw4; c4 += 256) dst[c4] = z;
    }
  }
}

extern "C" void kernel_launch(void* const* d_in, const int* in_sizes, int n_in,
                              void* d_out, int out_size, void* d_ws, size_t ws_size,
                              hipStream_t stream) {
  (void)in_sizes; (void)n_in; (void)out_size; (void)d_ws; (void)ws_size;
  const float* q = (const float*)d_in[0];
  const float* k = (const float*)d_in[1];
  const float* v = (const float*)d_in[2];
  float* out = (float*)d_out;
  sdpa_fused<<<dim3(1024), dim3(256), 0, stream>>>(q, k, v, out);
}